// Round 10
// baseline (185.263 us; speedup 1.0000x reference)
//
#include <hip/hip_runtime.h>
#include <math.h>

// ---------------- problem constants ----------------
constexpr int BATCH   = 8;
constexpr int NUM_CLS = 80;
constexpr int N0 = 19 * 19 * 3;   // 1083  (stride 32)
constexpr int N1 = 38 * 38 * 3;   // 4332  (stride 16)
constexpr int N2 = 76 * 76 * 3;   // 17328 (stride 8)
constexpr int OFF1 = N0;          // 1083
constexpr int OFF2 = N0 + N1;     // 5415
constexpr int NTOT = N0 + N1 + N2; // 22743 per image
constexpr int TOPN = 1000;
constexpr int NSEL = 3 * TOPN;    // 3000 per image
constexpr int MAXDET = 100;
constexpr float MIN_SCORE_F = 0.05f;
constexpr int IMG_MAX = 607;

__device__ __forceinline__ float sigmoidf_(float x) {
    return 1.0f / (1.0f + expf(-x));
}

// base anchor sizes (ANCHOR_WH); ref uses (wh*stride)/stride == wh exactly
// (stride is a power of two -> mul+div is an exact exponent shift in fp32).
__constant__ float AWH[3][3][2] = {
    {{116.f, 90.f}, {156.f, 198.f}, {373.f, 326.f}},  // lvl0, stride 32
    {{ 30.f, 61.f}, { 62.f,  45.f}, { 59.f, 119.f}},  // lvl1, stride 16
    {{ 10.f, 13.f}, { 16.f,  30.f}, { 33.f,  23.f}},  // lvl2, stride 8
};

// IoU > 0.5 test, arithmetic identical (incl. op order) to the verified k_iou.
__device__ __forceinline__ bool iou_gt(float4 a, float4 c) {
    float ai = (a.z - a.x) * (a.w - a.y);
    float aj = (c.z - c.x) * (c.w - c.y);
    float xx1 = fmaxf(a.x, c.x);
    float yy1 = fmaxf(a.y, c.y);
    float xx2 = fminf(a.z, c.z);
    float yy2 = fminf(a.w, c.w);
    float inter = fmaxf(xx2 - xx1, 0.0f) * fmaxf(yy2 - yy1, 0.0f);
    float uni = ai + aj - inter;
    return (inter > 0.5f * uni) && (inter > 0.0f);
}

// ---------------- K1: decode scores only -> packed key ----------------
// Key layout (64b): score_bits(32) << 22 | (Nl - n)(15b) << 7 | class(7b).
// Comparison order: score desc, then index asc (Nl-n unique per level), class
// never compared (index unique) -> identical total order to the verified key.
// Boxes are NOT decoded here: only the 3x1000 selected candidates need boxes,
// k_select decodes them from reg analytically (saves decB/decC entirely).
__global__ __launch_bounds__(256) void k_decode(
    const float* __restrict__ obj0, const float* __restrict__ cls0,
    const float* __restrict__ obj1, const float* __restrict__ cls1,
    const float* __restrict__ obj2, const float* __restrict__ cls2,
    unsigned long long* __restrict__ decKey,
    int* __restrict__ gflagImg, int* __restrict__ fbCursor)
{
    if (blockIdx.x == 0 && threadIdx.x < 32) {
        if (threadIdx.x < 8)  gflagImg[threadIdx.x] = 0;
        if (threadIdx.x < 24) fbCursor[threadIdx.x] = 0;
    }

    __shared__ float sBest[64];
    __shared__ int   sCls[64];

    int g0 = blockIdx.x * 64;
    int t  = threadIdx.x;

    // ---- phase A: class max, 4 lanes per candidate ----
    {
        int q  = t >> 2;          // candidate slot within block (0..63)
        int lq = t & 3;           // lane within group
        int idx = g0 + q;
        if (idx < BATCH * NTOT) {
            int b  = idx / NTOT;
            int na = idx - b * NTOT;
            const float* cls; int Nl, n;
            if (na < OFF1)      { cls = cls0; Nl = N0; n = na; }
            else if (na < OFF2) { cls = cls1; Nl = N1; n = na - OFF1; }
            else                { cls = cls2; Nl = N2; n = na - OFF2; }
            size_t bn = (size_t)b * Nl + n;

            const float4* cv = reinterpret_cast<const float4*>(cls + bn * NUM_CLS);
            float best = -1.0f; int bc = 0;
            #pragma unroll
            for (int k = 0; k < 5; ++k) {
                int m = lq + 4 * k;          // float4 index 0..19, classes 4m..4m+3
                float4 v = cv[m];
                float s;
                s = sigmoidf_(v.x); if (s > best) { best = s; bc = 4 * m + 0; }
                s = sigmoidf_(v.y); if (s > best) { best = s; bc = 4 * m + 1; }
                s = sigmoidf_(v.z); if (s > best) { best = s; bc = 4 * m + 2; }
                s = sigmoidf_(v.w); if (s > best) { best = s; bc = 4 * m + 3; }
            }
            #pragma unroll
            for (int d = 1; d <= 2; d <<= 1) {
                float ob = __shfl_xor(best, d);
                int   oc = __shfl_xor(bc, d);
                if (ob > best || (ob == best && oc < bc)) { best = ob; bc = oc; }
            }
            if (lq == 0) { sBest[q] = best; sCls[q] = bc; }
        }
    }
    __syncthreads();

    // ---- phase B: obj sigmoid + key write, 64 threads ----
    if (t < 64) {
        int idx = g0 + t;
        if (idx < BATCH * NTOT) {
            int b  = idx / NTOT;
            int na = idx - b * NTOT;
            const float* obj;
            int Nl, n;
            if (na < OFF1)      { obj = obj0; Nl = N0; n = na;        }
            else if (na < OFF2) { obj = obj1; Nl = N1; n = na - OFF1; }
            else                { obj = obj2; Nl = N2; n = na - OFF2; }
            size_t bn = (size_t)b * Nl + n;

            float so    = sigmoidf_(obj[bn]);
            float score = sBest[t] * so;
            int   bc    = sCls[t];

            size_t gg = (size_t)b * NTOT + na;
            decKey[gg] = ((unsigned long long)__float_as_uint(score) << 22)
                       | ((unsigned long long)(unsigned)(Nl - n) << 7)
                       | (unsigned)bc;
        }
    }
}

// ---------------- K2: exact per-level top-1000, PLACED IN SORTED ORDER -------
// Register-batched (round-9 win): keys loaded once into registers, histogram
// + placement replay from registers. writeOut now has ONE scattered read
// (reg float4 for the box decode) instead of three (key re-read + decC + decB
// are gone; key comes from LDS stKey, class from the key's low bits).
constexpr int NBIN  = 4096;
constexpr int STCAP = 2048;
constexpr int KPT   = 17;   // ceil(N2 / 1024)

__global__ __launch_bounds__(1024) void k_select(
    const unsigned long long* __restrict__ decKey,
    const float* __restrict__ reg0, const float* __restrict__ reg1,
    const float* __restrict__ reg2,
    float* __restrict__ selB, unsigned long long* __restrict__ selKey,
    int* __restrict__ gflagImg, int* __restrict__ fbCursor)
{
    __shared__ unsigned hist[NBIN];            // counts, then per-bucket cursor/cnt
    __shared__ unsigned cum[NBIN];             // strictly-higher counts
    __shared__ unsigned wscan[32];             // [0:16) wave sums, [16:32) wave suffixes
    __shared__ unsigned long long stKey[STCAP];
    __shared__ int stIdx[STCAP];
    __shared__ int sTot; __shared__ int sOvf;
    __shared__ int sBstar; __shared__ int sNeed;

    int b   = blockIdx.x / 3;
    int lvl = blockIdx.x % 3;
    int off = (lvl == 0) ? 0 : (lvl == 1) ? OFF1 : OFF2;
    int Nl  = (lvl == 0) ? N0 : (lvl == 1) ? N1 : N2;
    int gsz = (lvl == 0) ? 19 : (lvl == 1) ? 38 : 76;
    float st = (lvl == 0) ? 32.f : (lvl == 1) ? 16.f : 8.f;
    const float* reg = (lvl == 0) ? reg0 : (lvl == 1) ? reg1 : reg2;
    int tid = threadIdx.x;
    int lane = tid & 63;
    int wv   = tid >> 6;

    const unsigned long long* keys = decKey + (size_t)b * NTOT + off;

    // ---- batched register load of this thread's keys (independent loads) ----
    unsigned long long kk[KPT];
    #pragma unroll
    for (int i = 0; i < KPT; ++i) {
        int t = tid + i * 1024;
        kk[i] = (t < Nl) ? keys[t] : 0ull;
    }

    for (int t = tid; t < NBIN; t += 1024) hist[t] = 0;
    if (tid == 0) { sTot = 0; sOvf = 0; }
    __syncthreads();

    #pragma unroll
    for (int i = 0; i < KPT; ++i) {
        int t = tid + i * 1024;
        if (t < Nl) atomicAdd(&hist[(unsigned)(kk[i] >> 42)], 1u);
    }
    __syncthreads();

    // ---- parallel suffix scan: cum[bin] = # keys in strictly-higher bins ----
    {
        uint4 hh = reinterpret_cast<uint4*>(hist)[tid];
        reinterpret_cast<uint4*>(hist)[tid] = make_uint4(0u, 0u, 0u, 0u);
        unsigned ssum = hh.x + hh.y + hh.z + hh.w;

        unsigned sfx = ssum;
        #pragma unroll
        for (int d = 1; d < 64; d <<= 1) {
            unsigned o = __shfl_down(sfx, d);
            if (lane + d < 64) sfx += o;
        }
        if (lane == 0) wscan[wv] = sfx;   // wave total
        __syncthreads();
        if (tid < 16) {
            unsigned v = wscan[tid];
            unsigned s2 = v;
            #pragma unroll
            for (int d = 1; d < 16; d <<= 1) {
                unsigned o = __shfl_down(s2, d);
                if (tid + d < 16) s2 += o;
            }
            wscan[16 + tid] = s2 - v;     // exclusive suffix over waves > tid
        }
        __syncthreads();
        unsigned Tt = wscan[16 + wv] + (sfx - ssum);
        unsigned c3 = Tt;
        unsigned c2 = c3 + hh.w;
        unsigned c1 = c2 + hh.z;
        unsigned c0 = c1 + hh.y;
        reinterpret_cast<uint4*>(cum)[tid] = make_uint4(c0, c1, c2, c3);
    }
    __syncthreads();

    // ---- pass 2: replay from registers (no global re-read) ----
    #pragma unroll
    for (int i = 0; i < KPT; ++i) {
        int t = tid + i * 1024;
        if (t < Nl) {
            unsigned long long k = kk[i];
            unsigned bin = (unsigned)(k >> 42);
            if (cum[bin] < (unsigned)TOPN) {
                unsigned c = atomicAdd(&hist[bin], 1u);
                unsigned p = cum[bin] + c;
                if (p < STCAP) { stKey[p] = k; stIdx[p] = t; }
                else sOvf = 1;
            }
        }
    }
    __syncthreads();

    // sTot = total stored-candidate count (uniform per-bin condition)
    {
        uint4 hh = reinterpret_cast<uint4*>(hist)[tid];
        uint4 cc = reinterpret_cast<uint4*>(cum)[tid];
        unsigned loc = 0;
        if (cc.x < (unsigned)TOPN) loc += hh.x;
        if (cc.y < (unsigned)TOPN) loc += hh.y;
        if (cc.z < (unsigned)TOPN) loc += hh.z;
        if (cc.w < (unsigned)TOPN) loc += hh.w;
        #pragma unroll
        for (int d = 1; d < 64; d <<= 1) loc += __shfl_down(loc, d);
        if (lane == 0 && loc) atomicAdd(&sTot, (int)loc);
    }
    __syncthreads();

    // writeOut: decode the box HERE (bit-identical arithmetic to the verified
    // decode phase B), class from key low bits, global key built from score.
    auto writeOut = [&](int t, int r, unsigned long long k) {
        float sraw = __uint_as_float((unsigned)(k >> 22));
        int   bc   = (int)(k & 0x7F);
        int G = off + t;
        // raw-score global key: order among score<=0.05 entries differs from ref
        // but is provably irrelevant (they never keep/suppress/output).
        unsigned long long gk =
            (((unsigned long long)(__float_as_uint(sraw) | 0x80000000u)) << 23) |
            ((unsigned long long)(unsigned)(NTOT - G) << 7) | (unsigned)bc;

        size_t bn = (size_t)b * Nl + t;
        float4 rv = reinterpret_cast<const float4*>(reg)[bn];
        int a    = t % 3;
        int cell = t / 3;
        int gx   = cell % gsz;
        int gy   = cell / gsz;
        float ax = (float)gx, ay = (float)gy;
        float aw = AWH[lvl][a][0], ah = AWH[lvl][a][1];
        float cx = (sigmoidf_(rv.x) + ax) * st;
        float cy = (sigmoidf_(rv.y) + ay) * st;
        float w  = expf(rv.z) * aw;   // == exp*(aw*st)/st exactly (st = 2^k)
        float h  = expf(rv.w) * ah;
        float x1f = cx - 0.5f * w;
        float y1f = cy - 0.5f * h;
        float x2f = w + x1f;
        float y2f = h + y1f;
        int x1 = (int)x1f, y1 = (int)y1f, x2 = (int)x2f, y2 = (int)y2f;
        x1 = (x1 < 0) ? 0 : x1;
        y1 = (y1 < 0) ? 0 : y1;
        x2 = (x2 > IMG_MAX) ? IMG_MAX : x2;
        y2 = (y2 > IMG_MAX) ? IMG_MAX : y2;

        int o = b * NSEL + lvl * TOPN + r;
        selKey[o] = gk;
        reinterpret_cast<float4*>(selB)[o] =
            make_float4((float)x1, (float)y1, (float)x2, (float)y2);
    };

    if (sOvf == 0) {
        int M = sTot;
        for (int p = tid; p < M; p += 1024) {
            unsigned long long k = stKey[p];
            unsigned bin = (unsigned)(k >> 42);
            unsigned start = cum[bin], end = start + hist[bin];
            int r = (int)start;
            for (unsigned q = start; q < end; ++q) r += (stKey[q] > k) ? 1 : 0;
            if (r < TOPN) writeOut(stIdx[p], r, k);
        }
    } else {
        // -------- never-expected exact fallback --------
        if (tid == 0) {
            gflagImg[b] = 1;
            int B = 0;
            for (int bin = NBIN - 1; bin >= 0; --bin) {
                if (cum[bin] <= (unsigned)(TOPN - 1) &&
                    cum[bin] + hist[bin] > (unsigned)(TOPN - 1)) { B = bin; break; }
            }
            sBstar = B; sNeed = TOPN - (int)cum[B];
        }
        __syncthreads();
        int Bstar = sBstar, need = sNeed;
        for (int t = tid; t < Nl; t += 1024) {
            unsigned long long k = keys[t];
            int bin = (int)(unsigned)(k >> 42);
            bool em = false;
            if (bin > Bstar) em = true;
            else if (bin == Bstar) {
                int r = 0;
                for (int j = 0; j < Nl; ++j) {
                    unsigned long long kj = keys[j];
                    r += ((int)(unsigned)(kj >> 42) == Bstar && kj > k) ? 1 : 0;
                }
                em = (r < need);
            }
            if (em) {
                int r = atomicAdd(&fbCursor[b * 3 + lvl], 1);
                writeOut(t, r, k);
            }
        }
    }
}

// ---------------- K3: fused merge + NMS + output (one block per image) -------
// Score/class travel inside selKey; selS/selC no longer exist. Output re-reads
// selKey for the <=100 kept entries only (one scattered round trip).
constexpr int NPT = 3;   // ceil(NSEL / 1024)

__global__ __launch_bounds__(1024) void k_nms(
    const float* __restrict__ selB, const unsigned long long* __restrict__ selKey,
    const int* __restrict__ gflagImg,
    float* __restrict__ out)
{
    __shared__ union {
        unsigned long long keys[NSEL];   // phase 1
        float4 boxes[NSEL];              // phase 2/3 (48 KB)
    } U;
    __shared__ int ord[NSEL];            // rank -> original sel index (12 KB)
    __shared__ float4 keptBox[MAXDET];
    __shared__ int keptRank[MAXDET];
    __shared__ int sPos; __shared__ int sNValid;

    int b = blockIdx.x, tid = threadIdx.x;
    const unsigned bits05 = __float_as_uint(MIN_SCORE_F);

    // batched independent loads: keys -> LDS (validity derived from key bits)
    bool vld[NPT];
    {
        unsigned long long kv[NPT];
        #pragma unroll
        for (int i = 0; i < NPT; ++i) {
            int t = tid + i * 1024;
            kv[i] = (t < NSEL) ? selKey[b * NSEL + t] : 0ull;
            vld[i] = (t < NSEL) &&
                     (((unsigned)(kv[i] >> 23) & 0x7FFFFFFFu) > bits05);
        }
        #pragma unroll
        for (int i = 0; i < NPT; ++i) {
            int t = tid + i * 1024;
            if (t < NSEL) U.keys[t] = kv[i];
        }
    }
    if (tid == 0) sNValid = 0;
    __syncthreads();
    int fb = gflagImg[b];

    // ---- phase 1: ranks (registers, compile-time indexed) ----
    int myR[NPT];
    int nvLoc = 0;
    #pragma unroll
    for (int i = 0; i < NPT; ++i) {
        int t = tid + i * 1024;
        myR[i] = -1;
        if (t < NSEL) {
            unsigned long long k = U.keys[t];
            int rank;
            if (!fb) {
                int l = t / TOPN;
                rank = t - l * TOPN;
                #pragma unroll
                for (int m = 0; m < 3; ++m) {
                    if (m == l) continue;
                    int base = m * TOPN, lo = 0, hi = TOPN;
                    while (lo < hi) {
                        int mid = (lo + hi) >> 1;
                        if (U.keys[base + mid] > k) lo = mid + 1; else hi = mid;
                    }
                    rank += lo;
                }
            } else {
                int r = 0;
                for (int j = 0; j < NSEL; ++j) r += (U.keys[j] > k) ? 1 : 0;
                rank = r;
            }
            myR[i] = rank;
            if (vld[i]) nvLoc++;
        }
    }
    #pragma unroll
    for (int d = 1; d < 64; d <<= 1) nvLoc += __shfl_down(nvLoc, d);
    if ((tid & 63) == 0 && nvLoc) atomicAdd(&sNValid, nvLoc);
    __syncthreads();   // all ranks computed; keys no longer needed

    // ---- phase 2: scatter boxes into rank order (overwrites keys) ----
    {
        float4 bb[NPT];
        #pragma unroll
        for (int i = 0; i < NPT; ++i) {
            int t = tid + i * 1024;
            bb[i] = (t < NSEL) ? reinterpret_cast<const float4*>(selB)[b * NSEL + t]
                               : make_float4(0.f, 0.f, 0.f, 0.f);
        }
        #pragma unroll
        for (int i = 0; i < NPT; ++i) {
            int t = tid + i * 1024;
            if (t < NSEL) { U.boxes[myR[i]] = bb[i]; ord[myR[i]] = t; }
        }
    }
    __syncthreads();

    // ---- phase 3: greedy NMS, wave 0 only ----
    if (tid < 64) {
        int lane = tid;
        int nValid = sNValid;
        int pos = 0;
        int nW = (nValid + 63) >> 6;
        for (int w = 0; w < nW && pos < MAXDET; ++w) {
            int j = w * 64 + lane;
            float4 bx = (j < NSEL) ? U.boxes[j]
                                   : make_float4(4e8f, 4e8f, -4e8f, -4e8f);
            bool valid = (j < nValid);
            bool sup = false;
            for (int q = 0; q < pos; ++q)           // broadcast LDS read
                sup = sup || iou_gt(keptBox[q], bx);
            unsigned long long live = __ballot(valid && !sup);
            while (live) {
                int p = __ffsll(live) - 1;          // lowest live rank (uniform)
                if (lane == 0) keptRank[pos] = w * 64 + p;
                if (lane == p) keptBox[pos] = bx;
                pos++;
                if (pos >= MAXDET) break;
                float kx = __shfl(bx.x, p), ky = __shfl(bx.y, p);
                float kz = __shfl(bx.z, p), kw = __shfl(bx.w, p);
                bool hit = iou_gt(make_float4(kx, ky, kz, kw), bx);
                live &= ~__ballot(hit);
                live &= ~(1ull << p);
            }
        }
        if (lane == 0) sPos = pos;
    }
    __syncthreads();

    // ---- output: score/class recovered from selKey (<=100 scattered reads) ----
    int pos = sPos;
    float* out_s = out + b * MAXDET;
    float* out_c = out + BATCH * MAXDET + b * MAXDET;
    float* out_b = out + 2 * BATCH * MAXDET + (size_t)b * MAXDET * 4;
    for (int t = tid; t < MAXDET; t += 1024) {
        if (t < pos) {
            int i = keptRank[t];
            int o = ord[i];
            unsigned long long gk = selKey[b * NSEL + o];
            float sraw = __uint_as_float((unsigned)(gk >> 23) & 0x7FFFFFFFu);
            float clsf = (float)(int)(gk & 0x7F);
            float4 bb = U.boxes[i];
            out_s[t] = sraw;           // kept => sraw > MIN_SCORE
            out_c[t] = clsf;
            out_b[t * 4 + 0] = bb.x; out_b[t * 4 + 1] = bb.y;
            out_b[t * 4 + 2] = bb.z; out_b[t * 4 + 3] = bb.w;
        } else {
            out_s[t] = -1.0f; out_c[t] = -1.0f;
            out_b[t * 4 + 0] = -1.0f; out_b[t * 4 + 1] = -1.0f;
            out_b[t * 4 + 2] = -1.0f; out_b[t * 4 + 3] = -1.0f;
        }
    }
}

// ---------------- host launcher ----------------
extern "C" void kernel_launch(void* const* d_in, const int* in_sizes, int n_in,
                              void* d_out, int out_size, void* d_ws, size_t ws_size,
                              hipStream_t stream) {
    (void)n_in; (void)out_size; (void)ws_size;

    bool dict = (in_sizes[2] == BATCH * N0 * NUM_CLS); // 693120
    const float *obj[3], *reg[3], *cls[3];
    for (int l = 0; l < 3; ++l) {
        obj[l] = (const float*)d_in[dict ? 4 * l + 0 : l];
        reg[l] = (const float*)d_in[dict ? 4 * l + 1 : 3 + l];
        cls[l] = (const float*)d_in[dict ? 4 * l + 2 : 6 + l];
    }

    char* ws = (char*)d_ws;
    size_t off = 0;
    auto take = [&](size_t bytes) -> void* {
        void* p = ws + off;
        off += (bytes + 255) & ~(size_t)255;
        return p;
    };
    int*                 gflagImg = (int*)take(BATCH * sizeof(int));
    int*                 fbCursor = (int*)take(BATCH * 3 * sizeof(int));
    unsigned long long*  decKey   = (unsigned long long*)take((size_t)BATCH * NTOT * 8);
    float*               selB     = (float*)take((size_t)BATCH * NSEL * 16);
    unsigned long long*  selKey   = (unsigned long long*)take((size_t)BATCH * NSEL * 8);

    int totalDec = BATCH * NTOT; // 181944
    k_decode<<<(totalDec + 63) / 64, 256, 0, stream>>>(
        obj[0], cls[0],
        obj[1], cls[1],
        obj[2], cls[2],
        decKey, gflagImg, fbCursor);

    k_select<<<BATCH * 3, 1024, 0, stream>>>(decKey, reg[0], reg[1], reg[2],
                                             selB, selKey,
                                             gflagImg, fbCursor);

    k_nms<<<BATCH, 1024, 0, stream>>>(selB, selKey, gflagImg,
                                      (float*)d_out);
}

// Round 11
// 167.034 us; speedup vs baseline: 1.1091x; 1.1091x over previous
//
#include <hip/hip_runtime.h>
#include <math.h>

// ---------------- problem constants ----------------
constexpr int BATCH   = 8;
constexpr int NUM_CLS = 80;
constexpr int N0 = 19 * 19 * 3;   // 1083  (stride 32)
constexpr int N1 = 38 * 38 * 3;   // 4332  (stride 16)
constexpr int N2 = 76 * 76 * 3;   // 17328 (stride 8)
constexpr int OFF1 = N0;          // 1083
constexpr int OFF2 = N0 + N1;     // 5415
constexpr int NTOT = N0 + N1 + N2; // 22743 per image
constexpr int TOPN = 1000;
constexpr int NSEL = 3 * TOPN;    // 3000 per image
constexpr int MAXDET = 100;
constexpr float MIN_SCORE_F = 0.05f;
constexpr int IMG_MAX = 607;

__device__ __forceinline__ float sigmoidf_(float x) {
    return 1.0f / (1.0f + expf(-x));
}

// base anchor sizes (ANCHOR_WH); ref uses (wh*stride)/stride == wh exactly
// (stride is a power of two -> mul+div is an exact exponent shift in fp32).
__constant__ float AWH[3][3][2] = {
    {{116.f, 90.f}, {156.f, 198.f}, {373.f, 326.f}},  // lvl0, stride 32
    {{ 30.f, 61.f}, { 62.f,  45.f}, { 59.f, 119.f}},  // lvl1, stride 16
    {{ 10.f, 13.f}, { 16.f,  30.f}, { 33.f,  23.f}},  // lvl2, stride 8
};

// IoU > 0.5 test, arithmetic identical (incl. op order) to the verified k_iou.
__device__ __forceinline__ bool iou_gt(float4 a, float4 c) {
    float ai = (a.z - a.x) * (a.w - a.y);
    float aj = (c.z - c.x) * (c.w - c.y);
    float xx1 = fmaxf(a.x, c.x);
    float yy1 = fmaxf(a.y, c.y);
    float xx2 = fminf(a.z, c.z);
    float yy2 = fminf(a.w, c.w);
    float inter = fmaxf(xx2 - xx1, 0.0f) * fmaxf(yy2 - yy1, 0.0f);
    float uni = ai + aj - inter;
    return (inter > 0.5f * uni) && (inter > 0.0f);
}

// ---------------- K1: decode scores only -> packed key ----------------
// Key layout (64b): score_bits(32) << 22 | (Nl - n)(15b) << 7 | class(7b).
// Comparison order: score desc, then index asc (Nl-n unique per level), class
// never compared (index unique) -> identical total order to the verified key.
// Histogram bin = k >> 40 = score_bits >> 18 (<= 4063 < NBIN) — round-10's
// k>>42 was a 4x bin-resolution loss (the +17us regression).
__global__ __launch_bounds__(256) void k_decode(
    const float* __restrict__ obj0, const float* __restrict__ cls0,
    const float* __restrict__ obj1, const float* __restrict__ cls1,
    const float* __restrict__ obj2, const float* __restrict__ cls2,
    unsigned long long* __restrict__ decKey,
    int* __restrict__ gflagImg, int* __restrict__ fbCursor)
{
    if (blockIdx.x == 0 && threadIdx.x < 32) {
        if (threadIdx.x < 8)  gflagImg[threadIdx.x] = 0;
        if (threadIdx.x < 24) fbCursor[threadIdx.x] = 0;
    }

    __shared__ float sBest[64];
    __shared__ int   sCls[64];

    int g0 = blockIdx.x * 64;
    int t  = threadIdx.x;

    // ---- phase A: class max, 4 lanes per candidate ----
    {
        int q  = t >> 2;          // candidate slot within block (0..63)
        int lq = t & 3;           // lane within group
        int idx = g0 + q;
        if (idx < BATCH * NTOT) {
            int b  = idx / NTOT;
            int na = idx - b * NTOT;
            const float* cls; int Nl, n;
            if (na < OFF1)      { cls = cls0; Nl = N0; n = na; }
            else if (na < OFF2) { cls = cls1; Nl = N1; n = na - OFF1; }
            else                { cls = cls2; Nl = N2; n = na - OFF2; }
            size_t bn = (size_t)b * Nl + n;

            const float4* cv = reinterpret_cast<const float4*>(cls + bn * NUM_CLS);
            float best = -1.0f; int bc = 0;
            #pragma unroll
            for (int k = 0; k < 5; ++k) {
                int m = lq + 4 * k;          // float4 index 0..19, classes 4m..4m+3
                float4 v = cv[m];
                float s;
                s = sigmoidf_(v.x); if (s > best) { best = s; bc = 4 * m + 0; }
                s = sigmoidf_(v.y); if (s > best) { best = s; bc = 4 * m + 1; }
                s = sigmoidf_(v.z); if (s > best) { best = s; bc = 4 * m + 2; }
                s = sigmoidf_(v.w); if (s > best) { best = s; bc = 4 * m + 3; }
            }
            #pragma unroll
            for (int d = 1; d <= 2; d <<= 1) {
                float ob = __shfl_xor(best, d);
                int   oc = __shfl_xor(bc, d);
                if (ob > best || (ob == best && oc < bc)) { best = ob; bc = oc; }
            }
            if (lq == 0) { sBest[q] = best; sCls[q] = bc; }
        }
    }
    __syncthreads();

    // ---- phase B: obj sigmoid + key write, 64 threads ----
    if (t < 64) {
        int idx = g0 + t;
        if (idx < BATCH * NTOT) {
            int b  = idx / NTOT;
            int na = idx - b * NTOT;
            const float* obj;
            int Nl, n;
            if (na < OFF1)      { obj = obj0; Nl = N0; n = na;        }
            else if (na < OFF2) { obj = obj1; Nl = N1; n = na - OFF1; }
            else                { obj = obj2; Nl = N2; n = na - OFF2; }
            size_t bn = (size_t)b * Nl + n;

            float so    = sigmoidf_(obj[bn]);
            float score = sBest[t] * so;
            int   bc    = sCls[t];

            size_t gg = (size_t)b * NTOT + na;
            decKey[gg] = ((unsigned long long)__float_as_uint(score) << 22)
                       | ((unsigned long long)(unsigned)(Nl - n) << 7)
                       | (unsigned)bc;
        }
    }
}

// ---------------- K2: exact per-level top-1000, PLACED IN SORTED ORDER -------
// Register-batched (round-9 win): keys loaded once into registers, histogram
// + placement replay from registers. writeOut has ONE scattered read (reg
// float4 for the box decode); key comes from LDS stKey, class from key bits.
constexpr int NBIN  = 4096;
constexpr int STCAP = 2048;
constexpr int KPT   = 17;   // ceil(N2 / 1024)

__global__ __launch_bounds__(1024) void k_select(
    const unsigned long long* __restrict__ decKey,
    const float* __restrict__ reg0, const float* __restrict__ reg1,
    const float* __restrict__ reg2,
    float* __restrict__ selB, unsigned long long* __restrict__ selKey,
    int* __restrict__ gflagImg, int* __restrict__ fbCursor)
{
    __shared__ unsigned hist[NBIN];            // counts, then per-bucket cursor/cnt
    __shared__ unsigned cum[NBIN];             // strictly-higher counts
    __shared__ unsigned wscan[32];             // [0:16) wave sums, [16:32) wave suffixes
    __shared__ unsigned long long stKey[STCAP];
    __shared__ int stIdx[STCAP];
    __shared__ int sTot; __shared__ int sOvf;
    __shared__ int sBstar; __shared__ int sNeed;

    int b   = blockIdx.x / 3;
    int lvl = blockIdx.x % 3;
    int off = (lvl == 0) ? 0 : (lvl == 1) ? OFF1 : OFF2;
    int Nl  = (lvl == 0) ? N0 : (lvl == 1) ? N1 : N2;
    int gsz = (lvl == 0) ? 19 : (lvl == 1) ? 38 : 76;
    float st = (lvl == 0) ? 32.f : (lvl == 1) ? 16.f : 8.f;
    const float* reg = (lvl == 0) ? reg0 : (lvl == 1) ? reg1 : reg2;
    int tid = threadIdx.x;
    int lane = tid & 63;
    int wv   = tid >> 6;

    const unsigned long long* keys = decKey + (size_t)b * NTOT + off;

    // ---- batched register load of this thread's keys (independent loads) ----
    unsigned long long kk[KPT];
    #pragma unroll
    for (int i = 0; i < KPT; ++i) {
        int t = tid + i * 1024;
        kk[i] = (t < Nl) ? keys[t] : 0ull;
    }

    for (int t = tid; t < NBIN; t += 1024) hist[t] = 0;
    if (tid == 0) { sTot = 0; sOvf = 0; }
    __syncthreads();

    #pragma unroll
    for (int i = 0; i < KPT; ++i) {
        int t = tid + i * 1024;
        if (t < Nl) atomicAdd(&hist[(unsigned)(kk[i] >> 40)], 1u);
    }
    __syncthreads();

    // ---- parallel suffix scan: cum[bin] = # keys in strictly-higher bins ----
    {
        uint4 hh = reinterpret_cast<uint4*>(hist)[tid];
        reinterpret_cast<uint4*>(hist)[tid] = make_uint4(0u, 0u, 0u, 0u);
        unsigned ssum = hh.x + hh.y + hh.z + hh.w;

        unsigned sfx = ssum;
        #pragma unroll
        for (int d = 1; d < 64; d <<= 1) {
            unsigned o = __shfl_down(sfx, d);
            if (lane + d < 64) sfx += o;
        }
        if (lane == 0) wscan[wv] = sfx;   // wave total
        __syncthreads();
        if (tid < 16) {
            unsigned v = wscan[tid];
            unsigned s2 = v;
            #pragma unroll
            for (int d = 1; d < 16; d <<= 1) {
                unsigned o = __shfl_down(s2, d);
                if (tid + d < 16) s2 += o;
            }
            wscan[16 + tid] = s2 - v;     // exclusive suffix over waves > tid
        }
        __syncthreads();
        unsigned Tt = wscan[16 + wv] + (sfx - ssum);
        unsigned c3 = Tt;
        unsigned c2 = c3 + hh.w;
        unsigned c1 = c2 + hh.z;
        unsigned c0 = c1 + hh.y;
        reinterpret_cast<uint4*>(cum)[tid] = make_uint4(c0, c1, c2, c3);
    }
    __syncthreads();

    // ---- pass 2: replay from registers (no global re-read) ----
    #pragma unroll
    for (int i = 0; i < KPT; ++i) {
        int t = tid + i * 1024;
        if (t < Nl) {
            unsigned long long k = kk[i];
            unsigned bin = (unsigned)(k >> 40);
            if (cum[bin] < (unsigned)TOPN) {
                unsigned c = atomicAdd(&hist[bin], 1u);
                unsigned p = cum[bin] + c;
                if (p < STCAP) { stKey[p] = k; stIdx[p] = t; }
                else sOvf = 1;
            }
        }
    }
    __syncthreads();

    // sTot = total stored-candidate count (uniform per-bin condition)
    {
        uint4 hh = reinterpret_cast<uint4*>(hist)[tid];
        uint4 cc = reinterpret_cast<uint4*>(cum)[tid];
        unsigned loc = 0;
        if (cc.x < (unsigned)TOPN) loc += hh.x;
        if (cc.y < (unsigned)TOPN) loc += hh.y;
        if (cc.z < (unsigned)TOPN) loc += hh.z;
        if (cc.w < (unsigned)TOPN) loc += hh.w;
        #pragma unroll
        for (int d = 1; d < 64; d <<= 1) loc += __shfl_down(loc, d);
        if (lane == 0 && loc) atomicAdd(&sTot, (int)loc);
    }
    __syncthreads();

    // writeOut: decode the box HERE (bit-identical arithmetic to the verified
    // decode phase B), class from key low bits, global key built from score.
    auto writeOut = [&](int t, int r, unsigned long long k) {
        float sraw = __uint_as_float((unsigned)(k >> 22));
        int   bc   = (int)(k & 0x7F);
        int G = off + t;
        // raw-score global key: order among score<=0.05 entries differs from ref
        // but is provably irrelevant (they never keep/suppress/output).
        unsigned long long gk =
            (((unsigned long long)(__float_as_uint(sraw) | 0x80000000u)) << 23) |
            ((unsigned long long)(unsigned)(NTOT - G) << 7) | (unsigned)bc;

        size_t bn = (size_t)b * Nl + t;
        float4 rv = reinterpret_cast<const float4*>(reg)[bn];
        int a    = t % 3;
        int cell = t / 3;
        int gx   = cell % gsz;
        int gy   = cell / gsz;
        float ax = (float)gx, ay = (float)gy;
        float aw = AWH[lvl][a][0], ah = AWH[lvl][a][1];
        float cx = (sigmoidf_(rv.x) + ax) * st;
        float cy = (sigmoidf_(rv.y) + ay) * st;
        float w  = expf(rv.z) * aw;   // == exp*(aw*st)/st exactly (st = 2^k)
        float h  = expf(rv.w) * ah;
        float x1f = cx - 0.5f * w;
        float y1f = cy - 0.5f * h;
        float x2f = w + x1f;
        float y2f = h + y1f;
        int x1 = (int)x1f, y1 = (int)y1f, x2 = (int)x2f, y2 = (int)y2f;
        x1 = (x1 < 0) ? 0 : x1;
        y1 = (y1 < 0) ? 0 : y1;
        x2 = (x2 > IMG_MAX) ? IMG_MAX : x2;
        y2 = (y2 > IMG_MAX) ? IMG_MAX : y2;

        int o = b * NSEL + lvl * TOPN + r;
        selKey[o] = gk;
        reinterpret_cast<float4*>(selB)[o] =
            make_float4((float)x1, (float)y1, (float)x2, (float)y2);
    };

    if (sOvf == 0) {
        int M = sTot;
        for (int p = tid; p < M; p += 1024) {
            unsigned long long k = stKey[p];
            unsigned bin = (unsigned)(k >> 40);
            unsigned start = cum[bin], end = start + hist[bin];
            int r = (int)start;
            for (unsigned q = start; q < end; ++q) r += (stKey[q] > k) ? 1 : 0;
            if (r < TOPN) writeOut(stIdx[p], r, k);
        }
    } else {
        // -------- never-expected exact fallback --------
        if (tid == 0) {
            gflagImg[b] = 1;
            int B = 0;
            for (int bin = NBIN - 1; bin >= 0; --bin) {
                if (cum[bin] <= (unsigned)(TOPN - 1) &&
                    cum[bin] + hist[bin] > (unsigned)(TOPN - 1)) { B = bin; break; }
            }
            sBstar = B; sNeed = TOPN - (int)cum[B];
        }
        __syncthreads();
        int Bstar = sBstar, need = sNeed;
        for (int t = tid; t < Nl; t += 1024) {
            unsigned long long k = keys[t];
            int bin = (int)(unsigned)(k >> 40);
            bool em = false;
            if (bin > Bstar) em = true;
            else if (bin == Bstar) {
                int r = 0;
                for (int j = 0; j < Nl; ++j) {
                    unsigned long long kj = keys[j];
                    r += ((int)(unsigned)(kj >> 40) == Bstar && kj > k) ? 1 : 0;
                }
                em = (r < need);
            }
            if (em) {
                int r = atomicAdd(&fbCursor[b * 3 + lvl], 1);
                writeOut(t, r, k);
            }
        }
    }
}

// ---------------- K3: fused merge + NMS + output (one block per image) -------
// Score/class travel inside selKey; selS/selC no longer exist. Output re-reads
// selKey for the <=100 kept entries only (one scattered round trip).
constexpr int NPT = 3;   // ceil(NSEL / 1024)

__global__ __launch_bounds__(1024) void k_nms(
    const float* __restrict__ selB, const unsigned long long* __restrict__ selKey,
    const int* __restrict__ gflagImg,
    float* __restrict__ out)
{
    __shared__ union {
        unsigned long long keys[NSEL];   // phase 1
        float4 boxes[NSEL];              // phase 2/3 (48 KB)
    } U;
    __shared__ int ord[NSEL];            // rank -> original sel index (12 KB)
    __shared__ float4 keptBox[MAXDET];
    __shared__ int keptRank[MAXDET];
    __shared__ int sPos; __shared__ int sNValid;

    int b = blockIdx.x, tid = threadIdx.x;
    const unsigned bits05 = __float_as_uint(MIN_SCORE_F);

    // batched independent loads: keys -> LDS (validity derived from key bits)
    bool vld[NPT];
    {
        unsigned long long kv[NPT];
        #pragma unroll
        for (int i = 0; i < NPT; ++i) {
            int t = tid + i * 1024;
            kv[i] = (t < NSEL) ? selKey[b * NSEL + t] : 0ull;
            vld[i] = (t < NSEL) &&
                     (((unsigned)(kv[i] >> 23) & 0x7FFFFFFFu) > bits05);
        }
        #pragma unroll
        for (int i = 0; i < NPT; ++i) {
            int t = tid + i * 1024;
            if (t < NSEL) U.keys[t] = kv[i];
        }
    }
    if (tid == 0) sNValid = 0;
    __syncthreads();
    int fb = gflagImg[b];

    // ---- phase 1: ranks (registers, compile-time indexed) ----
    int myR[NPT];
    int nvLoc = 0;
    #pragma unroll
    for (int i = 0; i < NPT; ++i) {
        int t = tid + i * 1024;
        myR[i] = -1;
        if (t < NSEL) {
            unsigned long long k = U.keys[t];
            int rank;
            if (!fb) {
                int l = t / TOPN;
                rank = t - l * TOPN;
                #pragma unroll
                for (int m = 0; m < 3; ++m) {
                    if (m == l) continue;
                    int base = m * TOPN, lo = 0, hi = TOPN;
                    while (lo < hi) {
                        int mid = (lo + hi) >> 1;
                        if (U.keys[base + mid] > k) lo = mid + 1; else hi = mid;
                    }
                    rank += lo;
                }
            } else {
                int r = 0;
                for (int j = 0; j < NSEL; ++j) r += (U.keys[j] > k) ? 1 : 0;
                rank = r;
            }
            myR[i] = rank;
            if (vld[i]) nvLoc++;
        }
    }
    #pragma unroll
    for (int d = 1; d < 64; d <<= 1) nvLoc += __shfl_down(nvLoc, d);
    if ((tid & 63) == 0 && nvLoc) atomicAdd(&sNValid, nvLoc);
    __syncthreads();   // all ranks computed; keys no longer needed

    // ---- phase 2: scatter boxes into rank order (overwrites keys) ----
    {
        float4 bb[NPT];
        #pragma unroll
        for (int i = 0; i < NPT; ++i) {
            int t = tid + i * 1024;
            bb[i] = (t < NSEL) ? reinterpret_cast<const float4*>(selB)[b * NSEL + t]
                               : make_float4(0.f, 0.f, 0.f, 0.f);
        }
        #pragma unroll
        for (int i = 0; i < NPT; ++i) {
            int t = tid + i * 1024;
            if (t < NSEL) { U.boxes[myR[i]] = bb[i]; ord[myR[i]] = t; }
        }
    }
    __syncthreads();

    // ---- phase 3: greedy NMS, wave 0 only ----
    if (tid < 64) {
        int lane = tid;
        int nValid = sNValid;
        int pos = 0;
        int nW = (nValid + 63) >> 6;
        for (int w = 0; w < nW && pos < MAXDET; ++w) {
            int j = w * 64 + lane;
            float4 bx = (j < NSEL) ? U.boxes[j]
                                   : make_float4(4e8f, 4e8f, -4e8f, -4e8f);
            bool valid = (j < nValid);
            bool sup = false;
            for (int q = 0; q < pos; ++q)           // broadcast LDS read
                sup = sup || iou_gt(keptBox[q], bx);
            unsigned long long live = __ballot(valid && !sup);
            while (live) {
                int p = __ffsll(live) - 1;          // lowest live rank (uniform)
                if (lane == 0) keptRank[pos] = w * 64 + p;
                if (lane == p) keptBox[pos] = bx;
                pos++;
                if (pos >= MAXDET) break;
                float kx = __shfl(bx.x, p), ky = __shfl(bx.y, p);
                float kz = __shfl(bx.z, p), kw = __shfl(bx.w, p);
                bool hit = iou_gt(make_float4(kx, ky, kz, kw), bx);
                live &= ~__ballot(hit);
                live &= ~(1ull << p);
            }
        }
        if (lane == 0) sPos = pos;
    }
    __syncthreads();

    // ---- output: score/class recovered from selKey (<=100 scattered reads) ----
    int pos = sPos;
    float* out_s = out + b * MAXDET;
    float* out_c = out + BATCH * MAXDET + b * MAXDET;
    float* out_b = out + 2 * BATCH * MAXDET + (size_t)b * MAXDET * 4;
    for (int t = tid; t < MAXDET; t += 1024) {
        if (t < pos) {
            int i = keptRank[t];
            int o = ord[i];
            unsigned long long gk = selKey[b * NSEL + o];
            float sraw = __uint_as_float((unsigned)(gk >> 23) & 0x7FFFFFFFu);
            float clsf = (float)(int)(gk & 0x7F);
            float4 bb = U.boxes[i];
            out_s[t] = sraw;           // kept => sraw > MIN_SCORE
            out_c[t] = clsf;
            out_b[t * 4 + 0] = bb.x; out_b[t * 4 + 1] = bb.y;
            out_b[t * 4 + 2] = bb.z; out_b[t * 4 + 3] = bb.w;
        } else {
            out_s[t] = -1.0f; out_c[t] = -1.0f;
            out_b[t * 4 + 0] = -1.0f; out_b[t * 4 + 1] = -1.0f;
            out_b[t * 4 + 2] = -1.0f; out_b[t * 4 + 3] = -1.0f;
        }
    }
}

// ---------------- host launcher ----------------
extern "C" void kernel_launch(void* const* d_in, const int* in_sizes, int n_in,
                              void* d_out, int out_size, void* d_ws, size_t ws_size,
                              hipStream_t stream) {
    (void)n_in; (void)out_size; (void)ws_size;

    bool dict = (in_sizes[2] == BATCH * N0 * NUM_CLS); // 693120
    const float *obj[3], *reg[3], *cls[3];
    for (int l = 0; l < 3; ++l) {
        obj[l] = (const float*)d_in[dict ? 4 * l + 0 : l];
        reg[l] = (const float*)d_in[dict ? 4 * l + 1 : 3 + l];
        cls[l] = (const float*)d_in[dict ? 4 * l + 2 : 6 + l];
    }

    char* ws = (char*)d_ws;
    size_t off = 0;
    auto take = [&](size_t bytes) -> void* {
        void* p = ws + off;
        off += (bytes + 255) & ~(size_t)255;
        return p;
    };
    int*                 gflagImg = (int*)take(BATCH * sizeof(int));
    int*                 fbCursor = (int*)take(BATCH * 3 * sizeof(int));
    unsigned long long*  decKey   = (unsigned long long*)take((size_t)BATCH * NTOT * 8);
    float*               selB     = (float*)take((size_t)BATCH * NSEL * 16);
    unsigned long long*  selKey   = (unsigned long long*)take((size_t)BATCH * NSEL * 8);

    int totalDec = BATCH * NTOT; // 181944
    k_decode<<<(totalDec + 63) / 64, 256, 0, stream>>>(
        obj[0], cls[0],
        obj[1], cls[1],
        obj[2], cls[2],
        decKey, gflagImg, fbCursor);

    k_select<<<BATCH * 3, 1024, 0, stream>>>(decKey, reg[0], reg[1], reg[2],
                                             selB, selKey,
                                             gflagImg, fbCursor);

    k_nms<<<BATCH, 1024, 0, stream>>>(selB, selKey, gflagImg,
                                      (float*)d_out);
}